// Round 11
// baseline (9481.536 us; speedup 1.0000x reference)
//
#include <hip/hip_runtime.h>

// ---------------------------------------------------------------------------
// DA-RNN forward, round 11: ONE batch row per block -> 1024 blocks x 256 thr
// (4 waves/block, 4 blocks/CU = 16 waves/CU, same VGPR-capped wave count as
// r8 but 4x independent blocks and 4-wave barriers instead of 8/16-wave).
// Gate GEMMs per-thread-column (no k-split barrier). f16 dot2, no-max
// softmax, fused y_tilde. Streams from L2 each step.
// ws (float slots): weights 641,024 | x1h 16,777,216 | buf 16,777,216
// ---------------------------------------------------------------------------

typedef unsigned int   uint;
typedef unsigned short ushort;
typedef _Float16 h2v __attribute__((ext_vector_type(2)));

#define O_WEH     0u          // [256 kp][128 j]  uints (We^T f16 kpairs)
#define O_WENCH   32768u      // [192 kp][1024 j] uints ([Wih_e;Whh_e]^T)
#define O_WDH     229376u     // [256 kp][256 kk] uints (Wd^T)
#define O_WHHDH   294912u     // [128 kp][1024 j] uints (Whh_d^T)
#define O_UDT     425984u     // [256][256] f32
#define O_UET     491520u     // [128][128] f32
#define O_W1T     507904u     // [512][256] f32
#define O_BENC    638976u
#define O_BDEC    640000u
#define W_FLOATS  641024u
#define O_X1H     641024u     // x1 f16 [1024][128][128 pair-uints]
#define O_BUF     17418240u   // Ux f16, then Udx f16
#define WS_FLOATS 34195456u

#define C2E 2.8853900817779268f   // 2*log2(e)
#define L2E 1.4426950408889634f   // log2(e)

#define FMA4(acc, s, w) \
  acc.x = fmaf((s), (w).x, acc.x); \
  acc.y = fmaf((s), (w).y, acc.y); \
  acc.z = fmaf((s), (w).z, acc.z); \
  acc.w = fmaf((s), (w).w, acc.w);

union H2U { uint u; h2v h; _Float16 hs[2]; };

__device__ __forceinline__ float fdot2u(uint w, uint s, float acc) {
  H2U a; a.u = w; H2U b; b.u = s;
  return __builtin_amdgcn_fdot2(a.h, b.h, acc, false);
}
__device__ __forceinline__ uint pk2(float lo, float hi) {   // RNE f16 pair
  H2U v; v.hs[0] = (_Float16)lo; v.hs[1] = (_Float16)hi; return v.u;
}
__device__ __forceinline__ float h2lo(uint u) { H2U v; v.u = u; return (float)v.hs[0]; }
__device__ __forceinline__ float h2hi(uint u) { H2U v; v.u = u; return (float)v.hs[1]; }

__device__ __forceinline__ float fsig(float x) {
  return __builtin_amdgcn_rcpf(1.f + __builtin_amdgcn_exp2f(-L2E * x));
}
__device__ __forceinline__ float fth(float x) {
  float r = __builtin_amdgcn_rcpf(1.f + __builtin_amdgcn_exp2f(C2E * x));
  return fmaf(-2.f, r, 1.f);
}

// 4 dot2 (uint4 weights, one state pair) into a quad
#define DOT4(w, s0) { \
  a0 = fdot2u(w.x, s0, a0); a1 = fdot2u(w.y, s0, a1); \
  a2 = fdot2u(w.z, s0, a2); a3 = fdot2u(w.w, s0, a3); }

// sigmoid-sum term for attention tanh: V*rcp(1+exp2(C2E*u + oh))
#define ATT_TERM(vv, uu, oo) \
  ((vv) * __builtin_amdgcn_rcpf(1.f + __builtin_amdgcn_exp2f(fmaf(C2E, (uu), (oo)))))

// ---------------------------------------------------------------------------
__global__ __launch_bounds__(256) void prep_k(
    const float* __restrict__ We,    const float* __restrict__ Wih_e,
    const float* __restrict__ Whh_e, const float* __restrict__ Wd,
    const float* __restrict__ Whh_d, const float* __restrict__ W1,
    const float* __restrict__ Ud,    const float* __restrict__ Ue,
    const float* __restrict__ bih_e, const float* __restrict__ bhh_e,
    const float* __restrict__ bih_d, const float* __restrict__ bhh_d,
    float* __restrict__ ws)
{
  uint* wsu = (uint*)ws;
  unsigned idx = blockIdx.x * 256u + threadIdx.x;
  if (idx >= W_FLOATS) return;
  if (idx < 32768u) {                         // WeH[kp][j]
    unsigned kp = idx >> 7, j = idx & 127u;
    wsu[O_WEH + idx] = pk2(We[j * 512u + 2u*kp], We[j * 512u + 2u*kp + 1u]);
  } else if (idx < 229376u) {                 // WencH[kp][j]
    unsigned rel = idx - 32768u;
    unsigned kp = rel >> 10, j = rel & 1023u;
    float v0, v1;
    if (kp < 64u) { v0 = Wih_e[j * 128u + 2u*kp];          v1 = Wih_e[j * 128u + 2u*kp + 1u]; }
    else { unsigned k0 = 2u*(kp - 64u); v0 = Whh_e[j * 256u + k0]; v1 = Whh_e[j * 256u + k0 + 1u]; }
    wsu[O_WENCH + rel] = pk2(v0, v1);
  } else if (idx < 294912u) {                 // WdH[kp][kk]
    unsigned rel = idx - 229376u;
    unsigned kp = rel >> 8, kk = rel & 255u;
    wsu[O_WDH + rel] = pk2(Wd[kk * 512u + 2u*kp], Wd[kk * 512u + 2u*kp + 1u]);
  } else if (idx < 425984u) {                 // WhhdH[kp][j]
    unsigned rel = idx - 294912u;
    unsigned kp = rel >> 10, j = rel & 1023u;
    wsu[O_WHHDH + rel] = pk2(Whh_d[j * 256u + 2u*kp], Whh_d[j * 256u + 2u*kp + 1u]);
  } else if (idx < 491520u) {                 // UdT[m][k]
    unsigned rel = idx - 425984u;
    unsigned m = rel >> 8, k = rel & 255u;
    ws[O_UDT + rel] = Ud[k * 256u + m];
  } else if (idx < 507904u) {                 // UeT[t][s]
    unsigned rel = idx - 491520u;
    unsigned t = rel >> 7, s = rel & 127u;
    ws[O_UET + rel] = Ue[s * 128u + t];
  } else if (idx < 638976u) {                 // W1T[k][q]
    unsigned rel = idx - 507904u;
    unsigned k = rel >> 8, q = rel & 255u;
    ws[O_W1T + rel] = W1[q * 512u + k];
  } else if (idx < 640000u) {
    unsigned rel = idx - 638976u;
    ws[O_BENC + rel] = bih_e[rel] + bhh_e[rel];
  } else {
    unsigned rel = idx - 640000u;
    ws[O_BDEC + rel] = bih_d[rel] + bhh_d[rel];
  }
}

// ---------------------------------------------------------------------------
// Ux[b][i][s] f16 = sum_t x[b][t][i]*Ue[s][t].  grid = 1024*4.
__global__ __launch_bounds__(256) void ux_k(
    const float* __restrict__ x, const float* __restrict__ UeT,
    uint* __restrict__ UxU)
{
  __shared__ float xs[128][32];
  const int b  = blockIdx.x >> 2;
  const int i0 = (blockIdx.x & 3) * 32;
  const int tid = threadIdx.x;
  for (int idx = tid; idx < 4096; idx += 256) {
    int t = idx >> 5, il = idx & 31;
    xs[t][il] = x[(size_t)b * 16384 + t * 128 + i0 + il];
  }
  __syncthreads();
  const int sl = tid & 31;
  const int ig = tid >> 5;
  const float4* UeT4 = (const float4*)UeT;
  float4 acc[4];
  #pragma unroll
  for (int ii = 0; ii < 4; ++ii) acc[ii] = make_float4(0.f, 0.f, 0.f, 0.f);
  for (int t = 0; t < 128; ++t) {
    float4 w = UeT4[t * 32 + sl];
    #pragma unroll
    for (int ii = 0; ii < 4; ++ii) {
      float a = xs[t][ig + 8 * ii];
      FMA4(acc[ii], a, w);
    }
  }
  uint2* U2 = (uint2*)UxU;
  #pragma unroll
  for (int ii = 0; ii < 4; ++ii) {
    int i_loc = i0 + ig + 8 * ii;
    uint2 pk;
    pk.x = pk2(acc[ii].x, acc[ii].y);
    pk.y = pk2(acc[ii].z, acc[ii].w);
    U2[((size_t)b * 128 + i_loc) * 32 + sl] = pk;
  }
}

// ---------------------------------------------------------------------------
// Udx[b][t][k] f16 = sum_m x1[b][t][m]*Ud[k][m].  grid = 1024*4.
__global__ __launch_bounds__(256) void udx_k(
    const uint* __restrict__ x1hU, const float* __restrict__ UdT,
    uint* __restrict__ UdxU)
{
  __shared__ float xs[32][256];
  const int b  = blockIdx.x >> 2;
  const int t0 = (blockIdx.x & 3) * 32;
  const int tid = threadIdx.x;
  const uint4* x14 = (const uint4*)x1hU + (size_t)b * 4096;
  for (int it = 0; it < 4; ++it) {
    int f = tid + it * 256;
    int tl = f >> 5, mq = f & 31;
    uint4 u = x14[(size_t)(t0 + tl) * 32 + mq];
    float* d = &xs[tl][mq * 8];
    d[0] = h2lo(u.x); d[1] = h2hi(u.x); d[2] = h2lo(u.y); d[3] = h2hi(u.y);
    d[4] = h2lo(u.z); d[5] = h2hi(u.z); d[6] = h2lo(u.w); d[7] = h2hi(u.w);
  }
  __syncthreads();
  const int kl = tid & 63;
  const int tg = tid >> 6;
  const float4* UdT4 = (const float4*)UdT;
  float4 acc[8];
  #pragma unroll
  for (int tt = 0; tt < 8; ++tt) acc[tt] = make_float4(0.f, 0.f, 0.f, 0.f);
  for (int m = 0; m < 256; ++m) {
    float4 w = UdT4[m * 64 + kl];
    #pragma unroll
    for (int tt = 0; tt < 8; ++tt) {
      float a = xs[tg + 4 * tt][m];
      FMA4(acc[tt], a, w);
    }
  }
  uint2* U2 = (uint2*)UdxU;
  #pragma unroll
  for (int tt = 0; tt < 8; ++tt) {
    uint2 pk;
    pk.x = pk2(acc[tt].x, acc[tt].y);
    pk.y = pk2(acc[tt].z, acc[tt].w);
    U2[((size_t)b * 128 + t0 + tg + 4 * tt) * 64 + kl] = pk;
  }
}

// ---------------------------------------------------------------------------
// Encoder: 1024 blocks * 256 threads, 1 row/block, 128 steps.
__global__ __launch_bounds__(256, 4) void encoder_k(
    const uint* __restrict__ WeH, const uint* __restrict__ WencH,
    const float* __restrict__ benc, const float* __restrict__ Ve,
    const uint* __restrict__ UxH, uint* __restrict__ x1hU)
{
  __shared__ uint stH[256];             // [h-pairs 0..127 | c-pairs 128..255]
  __shared__ uint xtH[64];
  __shared__ __align__(16) float part[1024];
  __shared__ float ohs2[128];           // C2E * ohs
  __shared__ float bencS[1024];
  __shared__ float VeS[128];
  __shared__ float red1[4];

  const int tid = threadIdx.x;
  const int b = blockIdx.x;

  stH[tid] = 0u;
  #pragma unroll
  for (int i = 0; i < 4; ++i) bencS[tid + i * 256] = benc[tid + i * 256];
  if (tid < 128) VeS[tid] = Ve[tid];
  __syncthreads();

  float SVe = 0.f;
  for (int s = 0; s < 128; ++s) SVe += Ve[s];

  const uint4* WeH4   = (const uint4*)WeH;     // [kp][32 j4]
  const uint4* WencH4 = (const uint4*)WencH;   // [kp][256 j4]
  float4* part4 = (float4*)part;

  const int iB = tid >> 1, sh = tid & 1;
  const uint4* ux4 = (const uint4*)UxH + ((size_t)b * 128 + iB) * 16 + sh * 8;

  float c_reg = 0.f;                    // cell state for j = tid

  for (int step = 0; step < 128; ++step) {
    // --- A: ohs = hs @ We^T (K=512): 32 j4 x 8 ks, 32 kp each
    {
      const int j4 = tid & 31, ks = tid >> 5;
      float a0 = 0.f, a1 = 0.f, a2 = 0.f, a3 = 0.f;
      const int kb = ks * 32;
      #pragma unroll 4
      for (int kp = kb; kp < kb + 32; ++kp) {
        uint4 w = WeH4[kp * 32 + j4];
        uint s0 = stH[kp];
        DOT4(w, s0);
      }
      part4[ks * 32 + j4] = make_float4(a0, a1, a2, a3);
    }
    __syncthreads();
    if (tid < 128) {
      float acc = 0.f;
      #pragma unroll
      for (int ks = 0; ks < 8; ++ks) acc += part[ks * 128 + tid];
      ohs2[tid] = acc * C2E;
    }
    __syncthreads();
    // --- B: e[i] = SVe - 2*sum_s Ve[s]*rcp(1+exp2(C2E*u + ohs2[s]))
    float e_val;
    {
      float a0 = 0.f, a1 = 0.f, a2 = 0.f, a3 = 0.f;
      #pragma unroll 2
      for (int so = 0; so < 8; ++so) {
        uint4 u = ux4[so];
        const int s = sh * 64 + so * 8;
        a0 += ATT_TERM(VeS[s+0], h2lo(u.x), ohs2[s+0]);
        a1 += ATT_TERM(VeS[s+1], h2hi(u.x), ohs2[s+1]);
        a2 += ATT_TERM(VeS[s+2], h2lo(u.y), ohs2[s+2]);
        a3 += ATT_TERM(VeS[s+3], h2hi(u.y), ohs2[s+3]);
        a0 += ATT_TERM(VeS[s+4], h2lo(u.z), ohs2[s+4]);
        a1 += ATT_TERM(VeS[s+5], h2hi(u.z), ohs2[s+5]);
        a2 += ATT_TERM(VeS[s+6], h2lo(u.w), ohs2[s+6]);
        a3 += ATT_TERM(VeS[s+7], h2hi(u.w), ohs2[s+7]);
      }
      float r4 = (a0 + a1) + (a2 + a3);
      r4 += __shfl_xor(r4, 1);          // combine the two s-halves
      e_val = fmaf(-2.f, r4, SVe);
    }
    // --- softmax over i (no max: |e| bounded); quirk xt = alpha*e
    {
      float p  = __builtin_amdgcn_exp2f(L2E * e_val);
      float ps = (sh == 0) ? p : 0.f;
      #pragma unroll
      for (int o = 1; o < 64; o <<= 1) ps += __shfl_xor(ps, o);
      if ((tid & 63) == 0) red1[tid >> 6] = ps;
      __syncthreads();
      float sm = (red1[0] + red1[1]) + (red1[2] + red1[3]);
      float xt = p * __builtin_amdgcn_rcpf(sm) * e_val;
      float xn = __shfl_down(xt, 2);
      if ((tid & 3) == 0) xtH[iB >> 1] = pk2(xt, xn);
    }
    __syncthreads();
    // --- D: gates[1024] = [xt;h] @ Wenc: per-thread column quad (no k-split)
    {
      float a0 = 0.f, a1 = 0.f, a2 = 0.f, a3 = 0.f;
      #pragma unroll 2
      for (int kp = 0; kp < 64; ++kp) {
        uint4 w = WencH4[kp * 256 + tid];
        uint s0 = xtH[kp];
        DOT4(w, s0);
      }
      #pragma unroll 2
      for (int kp = 64; kp < 192; ++kp) {
        uint4 w = WencH4[kp * 256 + tid];
        uint s0 = stH[kp - 64];
        DOT4(w, s0);
      }
      part4[tid] = make_float4(a0, a1, a2, a3);
    }
    __syncthreads();
    // --- update: gates -> h2,c2 (cell in register); pack pairs via shfl
    {
      const int j = tid;
      float z0 = bencS[j]       + part[j];
      float z1 = bencS[256 + j] + part[256 + j];
      float z2 = bencS[512 + j] + part[512 + j];
      float z3 = bencS[768 + j] + part[768 + j];
      float gi = fsig(z0), gf = fsig(z1), gg = fth(z2), go = fsig(z3);
      float c2 = fmaf(gf, c_reg, gi * gg);
      c_reg = c2;
      float h2 = go * fth(c2);
      float hn = __shfl_down(h2, 1);
      float cn = __shfl_down(c2, 1);
      if (!(j & 1)) {
        uint hp = pk2(h2, hn), cp = pk2(c2, cn);
        stH[j >> 1] = hp;
        stH[128 + (j >> 1)] = cp;
        x1hU[((size_t)b * 128 + step) * 128 + (j >> 1)] = hp;
      }
    }
    __syncthreads();
  }
}

// ---------------------------------------------------------------------------
// Decoder + head: 1024 blocks * 256 threads, 1 row/block, 128 steps.
__global__ __launch_bounds__(256, 4) void decoder_k(
    const uint* __restrict__ WdH, const uint* __restrict__ WhhdH,
    const float* __restrict__ W1T, const float* __restrict__ bdec,
    const float* __restrict__ Vd,  const float* __restrict__ WihD,
    const float* __restrict__ Wt,  const float* __restrict__ btp,
    const float* __restrict__ b1,  const float* __restrict__ W2,
    const float* __restrict__ b2p, const float* __restrict__ yk,
    const uint* __restrict__ UdxH, const uint* __restrict__ x1hU,
    float* __restrict__ out)
{
  __shared__ uint stH[256];             // [d-pairs | c-pairs]
  __shared__ __align__(16) float part[2048];
  __shared__ float ods2[256];           // C2E * ods
  __shared__ float cT[256];
  __shared__ float betaS[128];
  __shared__ float wihdS[1024];
  __shared__ float bdecS[1024];
  __shared__ float VdS[256];
  __shared__ float ytS;
  __shared__ float red1[4];
  __shared__ float red2[4];
  __shared__ float red3[4];

  const int tid = threadIdx.x;
  const int b = blockIdx.x;

  stH[tid] = 0u;
  #pragma unroll
  for (int i = 0; i < 4; ++i) {
    wihdS[tid + i * 256] = WihD[tid + i * 256];
    bdecS[tid + i * 256] = bdec[tid + i * 256];
  }
  VdS[tid] = Vd[tid];
  __syncthreads();

  float SVd = 0.f;
  for (int k = 0; k < 256; ++k) SVd += Vd[k];

  const float bt0 = btp[0], Wt0 = Wt[0];
  const uint4*  WdH4   = (const uint4*)WdH;     // [kp][64 j4]
  const uint4*  WhhdH4 = (const uint4*)WhhdH;   // [kp][256 j4]
  const float*  W1Tf   = W1T;
  float4* part4 = (float4*)part;

  const int tB = tid >> 1, kh = tid & 1;
  const uint4* ud4 = (const uint4*)UdxH + ((size_t)b * 128 + tB) * 32 + kh * 16;
  const int mc = tid & 31, ts = tid >> 5;
  const uint2* x12 = (const uint2*)x1hU + (size_t)b * 8192;

  float c_reg = 0.f;

  for (int step = 0; step < 128; ++step) {
    // --- A: ods = ds @ Wd^T (K=512): 64 j4 x 4 ks, 64 kp each
    {
      const int j4 = tid & 63, ks = tid >> 6;
      float a0 = 0.f, a1 = 0.f, a2 = 0.f, a3 = 0.f;
      const int kb = ks * 64;
      #pragma unroll 4
      for (int kp = kb; kp < kb + 64; ++kp) {
        uint4 w = WdH4[kp * 64 + j4];
        uint s0 = stH[kp];
        DOT4(w, s0);
      }
      part4[ks * 64 + j4] = make_float4(a0, a1, a2, a3);
    }
    __syncthreads();
    {
      float acc = part[tid] + part[256 + tid] + part[512 + tid] + part[768 + tid];
      ods2[tid] = acc * C2E;
    }
    __syncthreads();
    // --- B: l[t] = SVd - 2*sum_k Vd[k]*rcp(1+exp2(C2E*u + ods2[k]))
    float l_val;
    {
      float a0 = 0.f, a1 = 0.f, a2 = 0.f, a3 = 0.f;
      #pragma unroll 2
      for (int ko = 0; ko < 16; ++ko) {
        uint4 u = ud4[ko];
        const int k = kh * 128 + ko * 8;
        a0 += ATT_TERM(VdS[k+0], h2lo(u.x), ods2[k+0]);
        a1 += ATT_TERM(VdS[k+1], h2hi(u.x), ods2[k+1]);
        a2 += ATT_TERM(VdS[k+2], h2lo(u.y), ods2[k+2]);
        a3 += ATT_TERM(VdS[k+3], h2hi(u.y), ods2[k+3]);
        a0 += ATT_TERM(VdS[k+4], h2lo(u.z), ods2[k+4]);
        a1 += ATT_TERM(VdS[k+5], h2hi(u.z), ods2[k+5]);
        a2 += ATT_TERM(VdS[k+6], h2lo(u.w), ods2[k+6]);
        a3 += ATT_TERM(VdS[k+7], h2hi(u.w), ods2[k+7]);
      }
      float r4 = (a0 + a1) + (a2 + a3);
      r4 += __shfl_xor(r4, 1);          // combine the two k-halves
      l_val = fmaf(-2.f, r4, SVd);
    }
    // --- softmax over t (no max: |l| bounded)
    {
      float p  = __builtin_amdgcn_exp2f(L2E * l_val);
      float ps = (kh == 0) ? p : 0.f;
      #pragma unroll
      for (int o = 1; o < 64; o <<= 1) ps += __shfl_xor(ps, o);
      if ((tid & 63) == 0) red1[tid >> 6] = ps;
      __syncthreads();
      float sm = (red1[0] + red1[1]) + (red1[2] + red1[3]);
      if (kh == 0) betaS[tB] = p * __builtin_amdgcn_rcpf(sm);
    }
    __syncthreads();
    // --- C: c[m] = sum_t beta[t]*x1[t][m]: 8 t-splits x 32 lanes, 16 t each
    {
      float c0=0,c1=0,c2=0,c3=0,c4=0,c5=0,c6=0,c7=0;
      const uint2* xr = x12 + mc;
      #pragma unroll 4
      for (int tt = 0; tt < 16; ++tt) {
        const int t = ts * 16 + tt;
        float bv = betaS[t];
        uint2 u  = xr[t * 64];
        uint2 u2 = xr[t * 64 + 32];
        c0 = fmaf(bv, h2lo(u.x),  c0); c1 = fmaf(bv, h2hi(u.x),  c1);
        c2 = fmaf(bv, h2lo(u.y),  c2); c3 = fmaf(bv, h2hi(u.y),  c3);
        c4 = fmaf(bv, h2lo(u2.x), c4); c5 = fmaf(bv, h2hi(u2.x), c5);
        c6 = fmaf(bv, h2lo(u2.y), c6); c7 = fmaf(bv, h2hi(u2.y), c7);
      }
      part4[ts * 64 + mc]      = make_float4(c0, c1, c2, c3);
      part4[ts * 64 + 32 + mc] = make_float4(c4, c5, c6, c7);
    }
    __syncthreads();
    // --- C-reduce + fused y_tilde row-dot
    {
      float v = 0.f;
      #pragma unroll
      for (int t8 = 0; t8 < 8; ++t8) v += part[t8 * 256 + tid];
      cT[tid] = v;
      float pv = v * Wt[1 + tid];
      #pragma unroll
      for (int o = 1; o < 64; o <<= 1) pv += __shfl_xor(pv, o);
      if ((tid & 63) == 0) red2[tid >> 6] = pv;
      __syncthreads();
      if (tid == 0) {
        float s = (red2[0] + red2[1]) + (red2[2] + red2[3]);
        ytS = s + yk[(size_t)b * 128 + step] * Wt0 + bt0;
      }
    }
    __syncthreads();
    // --- E: gates[1024] = d @ Whh_d^T: per-thread column quad (no k-split)
    {
      float a0 = 0.f, a1 = 0.f, a2 = 0.f, a3 = 0.f;
      #pragma unroll 2
      for (int kp = 0; kp < 128; ++kp) {
        uint4 w = WhhdH4[kp * 256 + tid];
        uint s0 = stH[kp];
        DOT4(w, s0);
      }
      part4[tid] = make_float4(a0, a1, a2, a3);
    }
    __syncthreads();
    // --- update
    {
      const int j = tid;
      float yt = ytS;
      float z0 = fmaf(yt, wihdS[j],       bdecS[j])       + part[j];
      float z1 = fmaf(yt, wihdS[256 + j], bdecS[256 + j]) + part[256 + j];
      float z2 = fmaf(yt, wihdS[512 + j], bdecS[512 + j]) + part[512 + j];
      float z3 = fmaf(yt, wihdS[768 + j], bdecS[768 + j]) + part[768 + j];
      float gi = fsig(z0), gf = fsig(z1), gg = fth(z2), go = fsig(z3);
      float c2 = fmaf(gf, c_reg, gi * gg);
      c_reg = c2;
      float d2 = go * fth(c2);
      float dn = __shfl_down(d2, 1);
      float cn = __shfl_down(c2, 1);
      if (!(j & 1)) {
        stH[j >> 1] = pk2(d2, dn);
        stH[128 + (j >> 1)] = pk2(c2, cn);
      }
    }
    __syncthreads();
  }
  // --- final head: out1 = [d;c] @ W1^T + b1 ; out = out1 @ W2^T + b2
  {
    const int q = tid;
    float o1 = b1[q];
    #pragma unroll 4
    for (int k = 0; k < 256; ++k) {
      uint u0 = stH[k >> 1];
      float dv = (k & 1) ? h2hi(u0) : h2lo(u0);
      o1 = fmaf(dv, W1Tf[k * 256 + q], o1);
    }
    #pragma unroll 4
    for (int k = 256; k < 512; ++k) {
      o1 = fmaf(cT[k - 256], W1Tf[k * 256 + q], o1);
    }
    float pv = o1 * W2[q];
    #pragma unroll
    for (int o = 1; o < 64; o <<= 1) pv += __shfl_xor(pv, o);
    if ((tid & 63) == 0) red3[tid >> 6] = pv;
    __syncthreads();
    if (tid == 0) {
      out[b] = (red3[0] + red3[1]) + (red3[2] + red3[3]) + b2p[0];
    }
  }
}

// ---------------------------------------------------------------------------
extern "C" void kernel_launch(void* const* d_in, const int* in_sizes, int n_in,
                              void* d_out, int out_size, void* d_ws, size_t ws_size,
                              hipStream_t stream)
{
  const float* x       = (const float*)d_in[0];
  const float* y_known = (const float*)d_in[1];
  const float* We      = (const float*)d_in[2];
  const float* Ue      = (const float*)d_in[3];
  const float* Ve      = (const float*)d_in[4];
  const float* Wih_e   = (const float*)d_in[5];
  const float* Whh_e   = (const float*)d_in[6];
  const float* bih_e   = (const float*)d_in[7];
  const float* bhh_e   = (const float*)d_in[8];
  const float* Wd      = (const float*)d_in[9];
  const float* Ud      = (const float*)d_in[10];
  const float* Vd      = (const float*)d_in[11];
  const float* Wih_d   = (const float*)d_in[12];
  const float* Whh_d   = (const float*)d_in[13];
  const float* bih_d   = (const float*)d_in[14];
  const float* bhh_d   = (const float*)d_in[15];
  const float* Wt      = (const float*)d_in[16];
  const float* bt      = (const float*)d_in[17];
  const float* W1      = (const float*)d_in[18];
  const float* b1      = (const float*)d_in[19];
  const float* W2      = (const float*)d_in[20];
  const float* b2      = (const float*)d_in[21];

  float* ws  = (float*)d_ws;
  float* out = (float*)d_out;
  if (ws_size < (size_t)WS_FLOATS * 4u) return;

  uint* wsu  = (uint*)ws;
  uint* x1hU = (uint*)(ws + O_X1H);
  uint* bufU = (uint*)(ws + O_BUF);   // Ux, then Udx

  prep_k<<<(W_FLOATS + 255) / 256, 256, 0, stream>>>(
      We, Wih_e, Whh_e, Wd, Whh_d, W1, Ud, Ue,
      bih_e, bhh_e, bih_d, bhh_d, ws);

  ux_k<<<4096, 256, 0, stream>>>(x, ws + O_UET, bufU);
  encoder_k<<<1024, 256, 0, stream>>>(wsu + O_WEH, wsu + O_WENCH,
                                      ws + O_BENC, Ve, bufU, x1hU);
  udx_k<<<4096, 256, 0, stream>>>(x1hU, ws + O_UDT, bufU);
  decoder_k<<<1024, 256, 0, stream>>>(wsu + O_WDH, wsu + O_WHHDH,
                                      ws + O_W1T, ws + O_BDEC, Vd, Wih_d,
                                      Wt, bt, b1, W2, b2, y_known,
                                      bufU, x1hU, out);
}

// Round 12
// 6981.088 us; speedup vs baseline: 1.3582x; 1.3582x over previous
//
#include <hip/hip_runtime.h>

// ---------------------------------------------------------------------------
// DA-RNN forward, round 12: r8 base (best-known: 512 blk x 512 thr, 2 rows,
// launch_bounds(512,4), f16 dot2, no-max softmax, fused y_tilde) plus:
//   - s_setprio(1) around dot2 GEMM clusters (2 indep blocks/CU arbitrate)
//   - phase-C x1 loads as uint4 (16B/lane, half the load instructions)
//   - yk scalar hoisted to step start; deeper unroll in phase B
// ws (float slots): weights 641,024 | x1h 16,777,216 | buf 16,777,216
// ---------------------------------------------------------------------------

typedef unsigned int   uint;
typedef unsigned short ushort;
typedef _Float16 h2v __attribute__((ext_vector_type(2)));

#define O_WEH     0u          // [256 kp][128 j]  uints (We^T f16 kpairs)
#define O_WENCH   32768u      // [192 kp][1024 j] uints ([Wih_e;Whh_e]^T)
#define O_WDH     229376u     // [256 kp][256 kk] uints (Wd^T)
#define O_WHHDH   294912u     // [128 kp][1024 j] uints (Whh_d^T)
#define O_UDT     425984u     // [256][256] f32
#define O_UET     491520u     // [128][128] f32
#define O_W1T     507904u     // [512][256] f32
#define O_BENC    638976u
#define O_BDEC    640000u
#define W_FLOATS  641024u
#define O_X1H     641024u     // x1 f16 [1024][128][128 pair-uints]
#define O_BUF     17418240u   // Ux f16, then Udx f16
#define WS_FLOATS 34195456u

#define C2E 2.8853900817779268f   // 2*log2(e)
#define L2E 1.4426950408889634f   // log2(e)

#define FMA4(acc, s, w) \
  acc.x = fmaf((s), (w).x, acc.x); \
  acc.y = fmaf((s), (w).y, acc.y); \
  acc.z = fmaf((s), (w).z, acc.z); \
  acc.w = fmaf((s), (w).w, acc.w);

union H2U { uint u; h2v h; _Float16 hs[2]; };

__device__ __forceinline__ float fdot2u(uint w, uint s, float acc) {
  H2U a; a.u = w; H2U b; b.u = s;
  return __builtin_amdgcn_fdot2(a.h, b.h, acc, false);
}
__device__ __forceinline__ uint pk2(float lo, float hi) {   // RNE f16 pair
  H2U v; v.hs[0] = (_Float16)lo; v.hs[1] = (_Float16)hi; return v.u;
}
__device__ __forceinline__ float h2lo(uint u) { H2U v; v.u = u; return (float)v.hs[0]; }
__device__ __forceinline__ float h2hi(uint u) { H2U v; v.u = u; return (float)v.hs[1]; }

__device__ __forceinline__ float fsig(float x) {
  return __builtin_amdgcn_rcpf(1.f + __builtin_amdgcn_exp2f(-L2E * x));
}
__device__ __forceinline__ float fth(float x) {
  float r = __builtin_amdgcn_rcpf(1.f + __builtin_amdgcn_exp2f(C2E * x));
  return fmaf(-2.f, r, 1.f);
}

// 8 dot2 (uint4 weights, two row-states) into a/b quads
#define DOT8(w, s0, s1) { \
  a0 = fdot2u(w.x, s0, a0); a1 = fdot2u(w.y, s0, a1); \
  a2 = fdot2u(w.z, s0, a2); a3 = fdot2u(w.w, s0, a3); \
  b0 = fdot2u(w.x, s1, b0); b1 = fdot2u(w.y, s1, b1); \
  b2 = fdot2u(w.z, s1, b2); b3 = fdot2u(w.w, s1, b3); }

// sigmoid-sum term for attention tanh: V*rcp(1+exp2(C2E*u + oh))
#define ATT_TERM(vv, uu, oo) \
  ((vv) * __builtin_amdgcn_rcpf(1.f + __builtin_amdgcn_exp2f(fmaf(C2E, (uu), (oo)))))

// ---------------------------------------------------------------------------
__global__ __launch_bounds__(256) void prep_k(
    const float* __restrict__ We,    const float* __restrict__ Wih_e,
    const float* __restrict__ Whh_e, const float* __restrict__ Wd,
    const float* __restrict__ Whh_d, const float* __restrict__ W1,
    const float* __restrict__ Ud,    const float* __restrict__ Ue,
    const float* __restrict__ bih_e, const float* __restrict__ bhh_e,
    const float* __restrict__ bih_d, const float* __restrict__ bhh_d,
    float* __restrict__ ws)
{
  uint* wsu = (uint*)ws;
  unsigned idx = blockIdx.x * 256u + threadIdx.x;
  if (idx >= W_FLOATS) return;
  if (idx < 32768u) {                         // WeH[kp][j]
    unsigned kp = idx >> 7, j = idx & 127u;
    wsu[O_WEH + idx] = pk2(We[j * 512u + 2u*kp], We[j * 512u + 2u*kp + 1u]);
  } else if (idx < 229376u) {                 // WencH[kp][j]
    unsigned rel = idx - 32768u;
    unsigned kp = rel >> 10, j = rel & 1023u;
    float v0, v1;
    if (kp < 64u) { v0 = Wih_e[j * 128u + 2u*kp];          v1 = Wih_e[j * 128u + 2u*kp + 1u]; }
    else { unsigned k0 = 2u*(kp - 64u); v0 = Whh_e[j * 256u + k0]; v1 = Whh_e[j * 256u + k0 + 1u]; }
    wsu[O_WENCH + rel] = pk2(v0, v1);
  } else if (idx < 294912u) {                 // WdH[kp][kk]
    unsigned rel = idx - 229376u;
    unsigned kp = rel >> 8, kk = rel & 255u;
    wsu[O_WDH + rel] = pk2(Wd[kk * 512u + 2u*kp], Wd[kk * 512u + 2u*kp + 1u]);
  } else if (idx < 425984u) {                 // WhhdH[kp][j]
    unsigned rel = idx - 294912u;
    unsigned kp = rel >> 10, j = rel & 1023u;
    wsu[O_WHHDH + rel] = pk2(Whh_d[j * 256u + 2u*kp], Whh_d[j * 256u + 2u*kp + 1u]);
  } else if (idx < 491520u) {                 // UdT[m][k]
    unsigned rel = idx - 425984u;
    unsigned m = rel >> 8, k = rel & 255u;
    ws[O_UDT + rel] = Ud[k * 256u + m];
  } else if (idx < 507904u) {                 // UeT[t][s]
    unsigned rel = idx - 491520u;
    unsigned t = rel >> 7, s = rel & 127u;
    ws[O_UET + rel] = Ue[s * 128u + t];
  } else if (idx < 638976u) {                 // W1T[k][q]
    unsigned rel = idx - 507904u;
    unsigned k = rel >> 8, q = rel & 255u;
    ws[O_W1T + rel] = W1[q * 512u + k];
  } else if (idx < 640000u) {
    unsigned rel = idx - 638976u;
    ws[O_BENC + rel] = bih_e[rel] + bhh_e[rel];
  } else {
    unsigned rel = idx - 640000u;
    ws[O_BDEC + rel] = bih_d[rel] + bhh_d[rel];
  }
}

// ---------------------------------------------------------------------------
// Ux[b][i][s] f16 = sum_t x[b][t][i]*Ue[s][t].  grid = 1024*4.
__global__ __launch_bounds__(256) void ux_k(
    const float* __restrict__ x, const float* __restrict__ UeT,
    uint* __restrict__ UxU)
{
  __shared__ float xs[128][32];
  const int b  = blockIdx.x >> 2;
  const int i0 = (blockIdx.x & 3) * 32;
  const int tid = threadIdx.x;
  for (int idx = tid; idx < 4096; idx += 256) {
    int t = idx >> 5, il = idx & 31;
    xs[t][il] = x[(size_t)b * 16384 + t * 128 + i0 + il];
  }
  __syncthreads();
  const int sl = tid & 31;
  const int ig = tid >> 5;
  const float4* UeT4 = (const float4*)UeT;
  float4 acc[4];
  #pragma unroll
  for (int ii = 0; ii < 4; ++ii) acc[ii] = make_float4(0.f, 0.f, 0.f, 0.f);
  for (int t = 0; t < 128; ++t) {
    float4 w = UeT4[t * 32 + sl];
    #pragma unroll
    for (int ii = 0; ii < 4; ++ii) {
      float a = xs[t][ig + 8 * ii];
      FMA4(acc[ii], a, w);
    }
  }
  uint2* U2 = (uint2*)UxU;
  #pragma unroll
  for (int ii = 0; ii < 4; ++ii) {
    int i_loc = i0 + ig + 8 * ii;
    uint2 pk;
    pk.x = pk2(acc[ii].x, acc[ii].y);
    pk.y = pk2(acc[ii].z, acc[ii].w);
    U2[((size_t)b * 128 + i_loc) * 32 + sl] = pk;
  }
}

// ---------------------------------------------------------------------------
// Udx[b][t][k] f16 = sum_m x1[b][t][m]*Ud[k][m].  grid = 1024*4.
__global__ __launch_bounds__(256) void udx_k(
    const uint* __restrict__ x1hU, const float* __restrict__ UdT,
    uint* __restrict__ UdxU)
{
  __shared__ float xs[32][256];
  const int b  = blockIdx.x >> 2;
  const int t0 = (blockIdx.x & 3) * 32;
  const int tid = threadIdx.x;
  const uint4* x14 = (const uint4*)x1hU + (size_t)b * 4096;
  for (int it = 0; it < 4; ++it) {
    int f = tid + it * 256;
    int tl = f >> 5, mq = f & 31;
    uint4 u = x14[(size_t)(t0 + tl) * 32 + mq];
    float* d = &xs[tl][mq * 8];
    d[0] = h2lo(u.x); d[1] = h2hi(u.x); d[2] = h2lo(u.y); d[3] = h2hi(u.y);
    d[4] = h2lo(u.z); d[5] = h2hi(u.z); d[6] = h2lo(u.w); d[7] = h2hi(u.w);
  }
  __syncthreads();
  const int kl = tid & 63;
  const int tg = tid >> 6;
  const float4* UdT4 = (const float4*)UdT;
  float4 acc[8];
  #pragma unroll
  for (int tt = 0; tt < 8; ++tt) acc[tt] = make_float4(0.f, 0.f, 0.f, 0.f);
  for (int m = 0; m < 256; ++m) {
    float4 w = UdT4[m * 64 + kl];
    #pragma unroll
    for (int tt = 0; tt < 8; ++tt) {
      float a = xs[tg + 4 * tt][m];
      FMA4(acc[tt], a, w);
    }
  }
  uint2* U2 = (uint2*)UdxU;
  #pragma unroll
  for (int tt = 0; tt < 8; ++tt) {
    uint2 pk;
    pk.x = pk2(acc[tt].x, acc[tt].y);
    pk.y = pk2(acc[tt].z, acc[tt].w);
    U2[((size_t)b * 128 + t0 + tg + 4 * tt) * 64 + kl] = pk;
  }
}

// ---------------------------------------------------------------------------
// Encoder: 512 blocks * 512 threads, 2 rows/block, 128 steps.
__global__ __launch_bounds__(512, 4) void encoder_k(
    const uint* __restrict__ WeH, const uint* __restrict__ WencH,
    const float* __restrict__ benc, const float* __restrict__ Ve,
    const uint* __restrict__ UxH, uint* __restrict__ x1hU)
{
  __shared__ uint stH[2][256];          // [h-pairs 0..127 | c-pairs 128..255]
  __shared__ uint xtH[2][64];
  __shared__ __align__(16) float part[4096];
  __shared__ float ohs2[2][128];        // C2E * ohs
  __shared__ float bencS[1024];
  __shared__ float VeS[128];
  __shared__ float red[8];

  const int tid = threadIdx.x;
  const int b0 = blockIdx.x * 2;

  ((uint*)stH)[tid] = 0u;
  for (int i = tid; i < 1024; i += 512) bencS[i] = benc[i];
  if (tid < 128) VeS[tid] = Ve[tid];
  __syncthreads();

  float SVe = 0.f;
  for (int s = 0; s < 128; ++s) SVe += Ve[s];

  const uint4* WeH4   = (const uint4*)WeH;     // [kp][32 j4]
  const uint4* WencH4 = (const uint4*)WencH;   // [kp][256 j4]
  float4* part4 = (float4*)part;

  const int rB = tid >> 8, iB = (tid >> 1) & 127, sh = tid & 1;
  const uint4* ux4 = (const uint4*)UxH + ((size_t)(b0 + rB) * 128 + iB) * 16 + sh * 8;

  float c_reg = 0.f;                    // cell state for (r=tid>>8, j=tid&255)

  for (int step = 0; step < 128; ++step) {
    // --- A: ohs = hs @ We^T (K=512): 32 j4 x 16 ks, 16 kp each
    {
      const int j4 = tid & 31, ks = tid >> 5;
      float a0=0,a1=0,a2=0,a3=0,b0=0,b1=0,b2=0,b3=0;
      const int kb = ks * 16;
      __builtin_amdgcn_s_setprio(1);
      #pragma unroll 4
      for (int kp = kb; kp < kb + 16; ++kp) {
        uint4 w = WeH4[kp * 32 + j4];
        uint s0 = stH[0][kp], s1 = stH[1][kp];
        DOT8(w, s0, s1);
      }
      __builtin_amdgcn_s_setprio(0);
      part4[(ks * 2 + 0) * 32 + j4] = make_float4(a0, a1, a2, a3);
      part4[(ks * 2 + 1) * 32 + j4] = make_float4(b0, b1, b2, b3);
    }
    __syncthreads();
    if (tid < 256) {
      const int r = tid >> 7, j = tid & 127;
      float acc = 0.f;
      #pragma unroll
      for (int ks = 0; ks < 16; ++ks) acc += part[(ks * 2 + r) * 128 + j];
      ohs2[r][j] = acc * C2E;
    }
    __syncthreads();
    // --- B: e[i] = SVe - 2*sum_s Ve[s]*rcp(1+exp2(C2E*u + ohs2[s]))
    float e_val;
    {
      float a0 = 0.f, a1 = 0.f, a2 = 0.f, a3 = 0.f;
      const float* oh = ohs2[rB];
      #pragma unroll 4
      for (int so = 0; so < 8; ++so) {
        uint4 u = ux4[so];
        const int s = sh * 64 + so * 8;
        a0 += ATT_TERM(VeS[s+0], h2lo(u.x), oh[s+0]);
        a1 += ATT_TERM(VeS[s+1], h2hi(u.x), oh[s+1]);
        a2 += ATT_TERM(VeS[s+2], h2lo(u.y), oh[s+2]);
        a3 += ATT_TERM(VeS[s+3], h2hi(u.y), oh[s+3]);
        a0 += ATT_TERM(VeS[s+4], h2lo(u.z), oh[s+4]);
        a1 += ATT_TERM(VeS[s+5], h2hi(u.z), oh[s+5]);
        a2 += ATT_TERM(VeS[s+6], h2lo(u.w), oh[s+6]);
        a3 += ATT_TERM(VeS[s+7], h2hi(u.w), oh[s+7]);
      }
      float r4 = (a0 + a1) + (a2 + a3);
      r4 += __shfl_xor(r4, 1);          // combine the two s-halves
      e_val = fmaf(-2.f, r4, SVe);
    }
    // --- softmax over i (no max: |e| <= sum|Ve| ~ 5); quirk xt = alpha*e
    {
      float p  = __builtin_amdgcn_exp2f(L2E * e_val);
      float ps = (sh == 0) ? p : 0.f;
      #pragma unroll
      for (int o = 1; o < 64; o <<= 1) ps += __shfl_xor(ps, o);
      if ((tid & 63) == 0) red[tid >> 6] = ps;
      __syncthreads();
      const int base = (tid >> 6) & 4;
      float sm = (red[base+0] + red[base+1]) + (red[base+2] + red[base+3]);
      float xt = p * __builtin_amdgcn_rcpf(sm) * e_val;
      float xn = __shfl_down(xt, 2);
      if ((tid & 3) == 0) xtH[rB][iB >> 1] = pk2(xt, xn);
    }
    __syncthreads();
    // --- D: gates = [xt;h] @ Wenc (K=384): 256 j4 x 2 ks, 96 kp each
    {
      const int j4 = tid & 255, ks = tid >> 8;
      float a0=0,a1=0,a2=0,a3=0,b0=0,b1=0,b2=0,b3=0;
      __builtin_amdgcn_s_setprio(1);
      if (ks == 0) {
        #pragma unroll 2
        for (int kp = 0; kp < 64; ++kp) {
          uint4 w = WencH4[kp * 256 + j4];
          uint s0 = xtH[0][kp], s1 = xtH[1][kp];
          DOT8(w, s0, s1);
        }
        #pragma unroll 2
        for (int kp = 64; kp < 96; ++kp) {
          uint4 w = WencH4[kp * 256 + j4];
          uint s0 = stH[0][kp - 64], s1 = stH[1][kp - 64];
          DOT8(w, s0, s1);
        }
      } else {
        #pragma unroll 2
        for (int kp = 96; kp < 192; ++kp) {
          uint4 w = WencH4[kp * 256 + j4];
          uint s0 = stH[0][kp - 64], s1 = stH[1][kp - 64];
          DOT8(w, s0, s1);
        }
      }
      __builtin_amdgcn_s_setprio(0);
      part4[(ks * 2 + 0) * 256 + j4] = make_float4(a0, a1, a2, a3);
      part4[(ks * 2 + 1) * 256 + j4] = make_float4(b0, b1, b2, b3);
    }
    __syncthreads();
    // --- update: gates -> h2,c2 (cell in register); pack pairs via shfl
    {
      const int r = tid >> 8, j = tid & 255;
      float z0 = bencS[j]       + part[r * 1024 + j]       + part[(2 + r) * 1024 + j];
      float z1 = bencS[256 + j] + part[r * 1024 + 256 + j] + part[(2 + r) * 1024 + 256 + j];
      float z2 = bencS[512 + j] + part[r * 1024 + 512 + j] + part[(2 + r) * 1024 + 512 + j];
      float z3 = bencS[768 + j] + part[r * 1024 + 768 + j] + part[(2 + r) * 1024 + 768 + j];
      float gi = fsig(z0), gf = fsig(z1), gg = fth(z2), go = fsig(z3);
      float c2 = fmaf(gf, c_reg, gi * gg);
      c_reg = c2;
      float h2 = go * fth(c2);
      float hn = __shfl_down(h2, 1);
      float cn = __shfl_down(c2, 1);
      if (!(j & 1)) {
        uint hp = pk2(h2, hn), cp = pk2(c2, cn);
        stH[r][j >> 1] = hp;
        stH[r][128 + (j >> 1)] = cp;
        x1hU[((size_t)(b0 + r) * 128 + step) * 128 + (j >> 1)] = hp;
      }
    }
    __syncthreads();
  }
}

// ---------------------------------------------------------------------------
// Decoder + head: 512 blocks * 512 threads, 2 rows/block, 128 steps.
__global__ __launch_bounds__(512, 4) void decoder_k(
    const uint* __restrict__ WdH, const uint* __restrict__ WhhdH,
    const float* __restrict__ W1T, const float* __restrict__ bdec,
    const float* __restrict__ Vd,  const float* __restrict__ WihD,
    const float* __restrict__ Wt,  const float* __restrict__ btp,
    const float* __restrict__ b1,  const float* __restrict__ W2,
    const float* __restrict__ b2p, const float* __restrict__ yk,
    const uint* __restrict__ UdxH, const uint* __restrict__ x1hU,
    float* __restrict__ out)
{
  __shared__ uint stH[2][256];          // [d-pairs | c-pairs]
  __shared__ __align__(16) float part[4096];
  __shared__ float ods2[2][256];        // C2E * ods
  __shared__ float cT[2][256];
  __shared__ float betaS[2][128];
  __shared__ float wihdS[1024];
  __shared__ float bdecS[1024];
  __shared__ float VdS[256];
  __shared__ float yts[2];
  __shared__ float red[8];

  const int tid = threadIdx.x;
  const int b0 = blockIdx.x * 2;

  ((uint*)stH)[tid] = 0u;
  for (int i = tid; i < 1024; i += 512) { wihdS[i] = WihD[i]; bdecS[i] = bdec[i]; }
  if (tid < 256) VdS[tid] = Vd[tid];
  __syncthreads();

  float SVd = 0.f;
  for (int k = 0; k < 256; ++k) SVd += Vd[k];

  const float bt0 = btp[0], Wt0 = Wt[0];
  const uint4*  WdH4   = (const uint4*)WdH;     // [kp][64 j4]
  const uint4*  WhhdH4 = (const uint4*)WhhdH;   // [kp][256 j4]
  const float4* W1T4   = (const float4*)W1T;
  float4* part4 = (float4*)part;

  const int rB = tid >> 8, tB = (tid >> 1) & 127, kh = tid & 1;
  const uint4* ud4 = (const uint4*)UdxH + ((size_t)(b0 + rB) * 128 + tB) * 32 + kh * 16;
  const int m8 = tid & 31, rb2 = (tid >> 5) & 1, ts = tid >> 6;
  const uint4* x14 = (const uint4*)x1hU + (size_t)(b0 + rb2) * 4096 + m8;

  float c_reg = 0.f;

  for (int step = 0; step < 128; ++step) {
    // hoist the per-step scalar yk load (consumed after phase C)
    float ykv = 0.f;
    if ((tid & 255) == 0) ykv = yk[(size_t)(b0 + (tid >> 8)) * 128 + step];
    // --- A: ods = ds @ Wd^T (K=512): 64 j4 x 8 ks, 32 kp each
    {
      const int j4 = tid & 63, ks = tid >> 6;
      float a0=0,a1=0,a2=0,a3=0,b0=0,b1=0,b2=0,b3=0;
      const int kb = ks * 32;
      __builtin_amdgcn_s_setprio(1);
      #pragma unroll 4
      for (int kp = kb; kp < kb + 32; ++kp) {
        uint4 w = WdH4[kp * 64 + j4];
        uint s0 = stH[0][kp], s1 = stH[1][kp];
        DOT8(w, s0, s1);
      }
      __builtin_amdgcn_s_setprio(0);
      part4[(ks * 2 + 0) * 64 + j4] = make_float4(a0, a1, a2, a3);
      part4[(ks * 2 + 1) * 64 + j4] = make_float4(b0, b1, b2, b3);
    }
    __syncthreads();
    {
      const int r = tid >> 8, kk = tid & 255;
      float acc = 0.f;
      #pragma unroll
      for (int ks = 0; ks < 8; ++ks) acc += part[(ks * 2 + r) * 256 + kk];
      ods2[r][kk] = acc * C2E;
    }
    __syncthreads();
    // --- B: l[t] = SVd - 2*sum_k Vd[k]*rcp(1+exp2(C2E*u + ods2[k]))
    float l_val;
    {
      float a0 = 0.f, a1 = 0.f, a2 = 0.f, a3 = 0.f;
      const float* od = ods2[rB];
      #pragma unroll 4
      for (int ko = 0; ko < 16; ++ko) {
        uint4 u = ud4[ko];
        const int k = kh * 128 + ko * 8;
        a0 += ATT_TERM(VdS[k+0], h2lo(u.x), od[k+0]);
        a1 += ATT_TERM(VdS[k+1], h2hi(u.x), od[k+1]);
        a2 += ATT_TERM(VdS[k+2], h2lo(u.y), od[k+2]);
        a3 += ATT_TERM(VdS[k+3], h2hi(u.y), od[k+3]);
        a0 += ATT_TERM(VdS[k+4], h2lo(u.z), od[k+4]);
        a1 += ATT_TERM(VdS[k+5], h2hi(u.z), od[k+5]);
        a2 += ATT_TERM(VdS[k+6], h2lo(u.w), od[k+6]);
        a3 += ATT_TERM(VdS[k+7], h2hi(u.w), od[k+7]);
      }
      float r4 = (a0 + a1) + (a2 + a3);
      r4 += __shfl_xor(r4, 1);          // combine the two k-halves
      l_val = fmaf(-2.f, r4, SVd);
    }
    // --- softmax over t (no max: |l| <= sum|Vd| ~ 10)
    {
      float p  = __builtin_amdgcn_exp2f(L2E * l_val);
      float ps = (kh == 0) ? p : 0.f;
      #pragma unroll
      for (int o = 1; o < 64; o <<= 1) ps += __shfl_xor(ps, o);
      if ((tid & 63) == 0) red[tid >> 6] = ps;
      __syncthreads();
      const int base = (tid >> 6) & 4;
      float sm = (red[base+0] + red[base+1]) + (red[base+2] + red[base+3]);
      if (kh == 0) betaS[rB][tB] = p * __builtin_amdgcn_rcpf(sm);
    }
    __syncthreads();
    // --- C: c[m] = sum_t beta[t]*x1[t][m]: lane owns 8 consecutive m (uint4)
    {
      float c0=0,c1=0,c2=0,c3=0,c4=0,c5=0,c6=0,c7=0;
      const float* bS = betaS[rb2];
      #pragma unroll 4
      for (int tt = 0; tt < 16; ++tt) {
        const int t = ts * 16 + tt;
        float bv = bS[t];
        uint4 u = x14[(size_t)t * 32];
        c0 = fmaf(bv, h2lo(u.x), c0); c1 = fmaf(bv, h2hi(u.x), c1);
        c2 = fmaf(bv, h2lo(u.y), c2); c3 = fmaf(bv, h2hi(u.y), c3);
        c4 = fmaf(bv, h2lo(u.z), c4); c5 = fmaf(bv, h2hi(u.z), c5);
        c6 = fmaf(bv, h2lo(u.w), c6); c7 = fmaf(bv, h2hi(u.w), c7);
      }
      part4[(ts * 2 + rb2) * 64 + m8 * 2]     = make_float4(c0, c1, c2, c3);
      part4[(ts * 2 + rb2) * 64 + m8 * 2 + 1] = make_float4(c4, c5, c6, c7);
    }
    __syncthreads();
    // --- C-reduce (linear) + fused y_tilde row-dot
    {
      const int r = tid >> 8, m = tid & 255;
      float v = 0.f;
      #pragma unroll
      for (int t8 = 0; t8 < 8; ++t8) v += part[(t8 * 2 + r) * 256 + m];
      cT[r][m] = v;
      float pv = v * Wt[1 + m];
      #pragma unroll
      for (int o = 1; o < 64; o <<= 1) pv += __shfl_xor(pv, o);
      if ((tid & 63) == 0) red[tid >> 6] = pv;
      __syncthreads();
      if ((tid & 255) == 0) {
        const int base = r * 4;
        float s = (red[base] + red[base+1]) + (red[base+2] + red[base+3]);
        yts[r] = s + ykv * Wt0 + bt0;
      }
    }
    // --- E: gates = d @ Whh_d^T (K=256): 256 j4 x 2 ks, 64 kp each
    {
      const int j4 = tid & 255, ks = tid >> 8;
      float a0=0,a1=0,a2=0,a3=0,b0=0,b1=0,b2=0,b3=0;
      const int kb = ks * 64;
      __builtin_amdgcn_s_setprio(1);
      #pragma unroll 2
      for (int kp = kb; kp < kb + 64; ++kp) {
        uint4 w = WhhdH4[kp * 256 + j4];
        uint s0 = stH[0][kp], s1 = stH[1][kp];
        DOT8(w, s0, s1);
      }
      __builtin_amdgcn_s_setprio(0);
      part4[(ks * 2 + 0) * 256 + j4] = make_float4(a0, a1, a2, a3);
      part4[(ks * 2 + 1) * 256 + j4] = make_float4(b0, b1, b2, b3);
    }
    __syncthreads();
    // --- update
    {
      const int r = tid >> 8, j = tid & 255;
      float yt = yts[r];
      float z0 = fmaf(yt, wihdS[j],       bdecS[j])       + part[r * 1024 + j]       + part[(2 + r) * 1024 + j];
      float z1 = fmaf(yt, wihdS[256 + j], bdecS[256 + j]) + part[r * 1024 + 256 + j] + part[(2 + r) * 1024 + 256 + j];
      float z2 = fmaf(yt, wihdS[512 + j], bdecS[512 + j]) + part[r * 1024 + 512 + j] + part[(2 + r) * 1024 + 512 + j];
      float z3 = fmaf(yt, wihdS[768 + j], bdecS[768 + j]) + part[r * 1024 + 768 + j] + part[(2 + r) * 1024 + 768 + j];
      float gi = fsig(z0), gf = fsig(z1), gg = fth(z2), go = fsig(z3);
      float c2 = fmaf(gf, c_reg, gi * gg);
      c_reg = c2;
      float d2 = go * fth(c2);
      float dn = __shfl_down(d2, 1);
      float cn = __shfl_down(c2, 1);
      if (!(j & 1)) {
        stH[r][j >> 1] = pk2(d2, dn);
        stH[r][128 + (j >> 1)] = pk2(c2, cn);
      }
    }
    __syncthreads();
  }
  // --- final head: out1 = [d;c] @ W1^T + b1 ; out = out1 @ W2^T + b2
  {
    const int l = tid & 63, ks = tid >> 6;   // 8 ks x 64 k
    float a0=0,a1=0,a2=0,a3=0,b0=0,b1=0,b2=0,b3=0;
    const int kb = ks * 64;
    if (ks < 4) {
      for (int k = kb; k < kb + 64; ++k) {
        float4 w = W1T4[k * 64 + l];
        uint u0 = stH[0][k >> 1], u1 = stH[1][k >> 1];
        float d0 = (k & 1) ? h2hi(u0) : h2lo(u0);
        float d1 = (k & 1) ? h2hi(u1) : h2lo(u1);
        a0=fmaf(d0,w.x,a0); a1=fmaf(d0,w.y,a1); a2=fmaf(d0,w.z,a2); a3=fmaf(d0,w.w,a3);
        b0=fmaf(d1,w.x,b0); b1=fmaf(d1,w.y,b1); b2=fmaf(d1,w.z,b2); b3=fmaf(d1,w.w,b3);
      }
    } else {
      for (int k = kb; k < kb + 64; ++k) {
        float4 w = W1T4[k * 64 + l];
        float c0 = cT[0][k - 256], c1 = cT[1][k - 256];
        a0=fmaf(c0,w.x,a0); a1=fmaf(c0,w.y,a1); a2=fmaf(c0,w.z,a2); a3=fmaf(c0,w.w,a3);
        b0=fmaf(c1,w.x,b0); b1=fmaf(c1,w.y,b1); b2=fmaf(c1,w.z,b2); b3=fmaf(c1,w.w,b3);
      }
    }
    part4[(ks * 2 + 0) * 64 + l] = make_float4(a0, a1, a2, a3);
    part4[(ks * 2 + 1) * 64 + l] = make_float4(b0, b1, b2, b3);
  }
  __syncthreads();
  {
    const int r = tid >> 8, q = tid & 255;
    float o1 = b1[q];
    #pragma unroll
    for (int ks = 0; ks < 8; ++ks) o1 += part[(ks * 2 + r) * 256 + q];
    float pv = o1 * W2[q];
    #pragma unroll
    for (int o = 1; o < 64; o <<= 1) pv += __shfl_xor(pv, o);
    if ((tid & 63) == 0) red[tid >> 6] = pv;
    __syncthreads();
    if ((tid & 255) == 0) {
      const int base = r * 4;
      float s = (red[base] + red[base+1]) + (red[base+2] + red[base+3]);
      out[b0 + r] = s + b2p[0];
    }
  }
}

// ---------------------------------------------------------------------------
extern "C" void kernel_launch(void* const* d_in, const int* in_sizes, int n_in,
                              void* d_out, int out_size, void* d_ws, size_t ws_size,
                              hipStream_t stream)
{
  const float* x       = (const float*)d_in[0];
  const float* y_known = (const float*)d_in[1];
  const float* We      = (const float*)d_in[2];
  const float* Ue      = (const float*)d_in[3];
  const float* Ve      = (const float*)d_in[4];
  const float* Wih_e   = (const float*)d_in[5];
  const float* Whh_e   = (const float*)d_in[6];
  const float* bih_e   = (const float*)d_in[7];
  const float* bhh_e   = (const float*)d_in[8];
  const float* Wd      = (const float*)d_in[9];
  const float* Ud      = (const float*)d_in[10];
  const float* Vd      = (const float*)d_in[11];
  const float* Wih_d   = (const float*)d_in[12];
  const float* Whh_d   = (const float*)d_in[13];
  const float* bih_d   = (const float*)d_in[14];
  const float* bhh_d   = (const float*)d_in[15];
  const float* Wt      = (const float*)d_in[16];
  const float* bt      = (const float*)d_in[17];
  const float* W1      = (const float*)d_in[18];
  const float* b1      = (const float*)d_in[19];
  const float* W2      = (const float*)d_in[20];
  const float* b2      = (const float*)d_in[21];

  float* ws  = (float*)d_ws;
  float* out = (float*)d_out;
  if (ws_size < (size_t)WS_FLOATS * 4u) return;

  uint* wsu  = (uint*)ws;
  uint* x1hU = (uint*)(ws + O_X1H);
  uint* bufU = (uint*)(ws + O_BUF);   // Ux, then Udx

  prep_k<<<(W_FLOATS + 255) / 256, 256, 0, stream>>>(
      We, Wih_e, Whh_e, Wd, Whh_d, W1, Ud, Ue,
      bih_e, bhh_e, bih_d, bhh_d, ws);

  ux_k<<<4096, 256, 0, stream>>>(x, ws + O_UET, bufU);
  encoder_k<<<512, 512, 0, stream>>>(wsu + O_WEH, wsu + O_WENCH,
                                     ws + O_BENC, Ve, bufU, x1hU);
  udx_k<<<4096, 256, 0, stream>>>(x1hU, ws + O_UDT, bufU);
  decoder_k<<<512, 512, 0, stream>>>(wsu + O_WDH, wsu + O_WHHDH,
                                     ws + O_W1T, ws + O_BDEC, Vd, Wih_d,
                                     Wt, bt, b1, W2, b2, y_known,
                                     bufU, x1hU, out);
}

// Round 13
// 6887.653 us; speedup vs baseline: 1.3766x; 1.0136x over previous
//
#include <hip/hip_runtime.h>

// ---------------------------------------------------------------------------
// DA-RNN forward, round 13: FUSED enc->udx->dec kernel (one launch, 512 blk x
// 512 thr, 2 rows/block, launch_bounds(512,4)). Rows are block-private =>
// no inter-block deps; blocks free-run through the whole pipeline.
// Workspace re-laid as per-row arenas (32768 float-slots each):
//   [0..16384)  x1 f16   [128 step][128 m-pair uints]
//   [16384..32768) B: Ux f16 (first 8192 uints) -> overwritten by Udx f16
// (Ux dead before Udx written, same block; other blocks never touch it.)
// LDS: one 48KB buffer, phase-unioned. All r12 micro-opts kept.
// ws: weights 641,024 | arenas 1024*32768 = 34,195,456 floats (=136.8MB).
// ---------------------------------------------------------------------------

typedef unsigned int   uint;
typedef unsigned short ushort;
typedef _Float16 h2v __attribute__((ext_vector_type(2)));

#define O_WEH     0u          // [256 kp][128 j]  uints (We^T f16 kpairs)
#define O_WENCH   32768u      // [192 kp][1024 j] uints ([Wih_e;Whh_e]^T)
#define O_WDH     229376u     // [256 kp][256 kk] uints (Wd^T)
#define O_WHHDH   294912u     // [128 kp][1024 j] uints (Whh_d^T)
#define O_UDT     425984u     // [256][256] f32
#define O_UET     491520u     // [128][128] f32
#define O_W1T     507904u     // [512][256] f32
#define O_BENC    638976u
#define O_BDEC    640000u
#define W_FLOATS  641024u
#define O_AR      641024u     // per-row arenas
#define WS_FLOATS 34195456u

#define C2E 2.8853900817779268f   // 2*log2(e)
#define L2E 1.4426950408889634f   // log2(e)

#define FMA4(acc, s, w) \
  acc.x = fmaf((s), (w).x, acc.x); \
  acc.y = fmaf((s), (w).y, acc.y); \
  acc.z = fmaf((s), (w).z, acc.z); \
  acc.w = fmaf((s), (w).w, acc.w);

union H2U { uint u; h2v h; _Float16 hs[2]; };

__device__ __forceinline__ float fdot2u(uint w, uint s, float acc) {
  H2U a; a.u = w; H2U b; b.u = s;
  return __builtin_amdgcn_fdot2(a.h, b.h, acc, false);
}
__device__ __forceinline__ uint pk2(float lo, float hi) {   // RNE f16 pair
  H2U v; v.hs[0] = (_Float16)lo; v.hs[1] = (_Float16)hi; return v.u;
}
__device__ __forceinline__ float h2lo(uint u) { H2U v; v.u = u; return (float)v.hs[0]; }
__device__ __forceinline__ float h2hi(uint u) { H2U v; v.u = u; return (float)v.hs[1]; }

__device__ __forceinline__ float fsig(float x) {
  return __builtin_amdgcn_rcpf(1.f + __builtin_amdgcn_exp2f(-L2E * x));
}
__device__ __forceinline__ float fth(float x) {
  float r = __builtin_amdgcn_rcpf(1.f + __builtin_amdgcn_exp2f(C2E * x));
  return fmaf(-2.f, r, 1.f);
}

#define DOT8(w, s0, s1) { \
  a0 = fdot2u(w.x, s0, a0); a1 = fdot2u(w.y, s0, a1); \
  a2 = fdot2u(w.z, s0, a2); a3 = fdot2u(w.w, s0, a3); \
  b0 = fdot2u(w.x, s1, b0); b1 = fdot2u(w.y, s1, b1); \
  b2 = fdot2u(w.z, s1, b2); b3 = fdot2u(w.w, s1, b3); }

#define ATT_TERM(vv, uu, oo) \
  ((vv) * __builtin_amdgcn_rcpf(1.f + __builtin_amdgcn_exp2f(fmaf(C2E, (uu), (oo)))))

// ---------------------------------------------------------------------------
__global__ __launch_bounds__(256) void prep_k(
    const float* __restrict__ We,    const float* __restrict__ Wih_e,
    const float* __restrict__ Whh_e, const float* __restrict__ Wd,
    const float* __restrict__ Whh_d, const float* __restrict__ W1,
    const float* __restrict__ Ud,    const float* __restrict__ Ue,
    const float* __restrict__ bih_e, const float* __restrict__ bhh_e,
    const float* __restrict__ bih_d, const float* __restrict__ bhh_d,
    float* __restrict__ ws)
{
  uint* wsu = (uint*)ws;
  unsigned idx = blockIdx.x * 256u + threadIdx.x;
  if (idx >= W_FLOATS) return;
  if (idx < 32768u) {                         // WeH[kp][j]
    unsigned kp = idx >> 7, j = idx & 127u;
    wsu[O_WEH + idx] = pk2(We[j * 512u + 2u*kp], We[j * 512u + 2u*kp + 1u]);
  } else if (idx < 229376u) {                 // WencH[kp][j]
    unsigned rel = idx - 32768u;
    unsigned kp = rel >> 10, j = rel & 1023u;
    float v0, v1;
    if (kp < 64u) { v0 = Wih_e[j * 128u + 2u*kp];          v1 = Wih_e[j * 128u + 2u*kp + 1u]; }
    else { unsigned k0 = 2u*(kp - 64u); v0 = Whh_e[j * 256u + k0]; v1 = Whh_e[j * 256u + k0 + 1u]; }
    wsu[O_WENCH + rel] = pk2(v0, v1);
  } else if (idx < 294912u) {                 // WdH[kp][kk]
    unsigned rel = idx - 229376u;
    unsigned kp = rel >> 8, kk = rel & 255u;
    wsu[O_WDH + rel] = pk2(Wd[kk * 512u + 2u*kp], Wd[kk * 512u + 2u*kp + 1u]);
  } else if (idx < 425984u) {                 // WhhdH[kp][j]
    unsigned rel = idx - 294912u;
    unsigned kp = rel >> 10, j = rel & 1023u;
    wsu[O_WHHDH + rel] = pk2(Whh_d[j * 256u + 2u*kp], Whh_d[j * 256u + 2u*kp + 1u]);
  } else if (idx < 491520u) {                 // UdT[m][k]
    unsigned rel = idx - 425984u;
    unsigned m = rel >> 8, k = rel & 255u;
    ws[O_UDT + rel] = Ud[k * 256u + m];
  } else if (idx < 507904u) {                 // UeT[t][s]
    unsigned rel = idx - 491520u;
    unsigned t = rel >> 7, s = rel & 127u;
    ws[O_UET + rel] = Ue[s * 128u + t];
  } else if (idx < 638976u) {                 // W1T[k][q]
    unsigned rel = idx - 507904u;
    unsigned k = rel >> 8, q = rel & 255u;
    ws[O_W1T + rel] = W1[q * 512u + k];
  } else if (idx < 640000u) {
    unsigned rel = idx - 638976u;
    ws[O_BENC + rel] = bih_e[rel] + bhh_e[rel];
  } else {
    unsigned rel = idx - 640000u;
    ws[O_BDEC + rel] = bih_d[rel] + bhh_d[rel];
  }
}

// ---------------------------------------------------------------------------
// Ux[b][i][s] f16 -> arena B region.  grid = 1024*4.
__global__ __launch_bounds__(256) void ux_k(
    const float* __restrict__ x, const float* __restrict__ UeT,
    uint* __restrict__ AR)
{
  __shared__ float xs[128][32];
  const int b  = blockIdx.x >> 2;
  const int i0 = (blockIdx.x & 3) * 32;
  const int tid = threadIdx.x;
  for (int idx = tid; idx < 4096; idx += 256) {
    int t = idx >> 5, il = idx & 31;
    xs[t][il] = x[(size_t)b * 16384 + t * 128 + i0 + il];
  }
  __syncthreads();
  const int sl = tid & 31;
  const int ig = tid >> 5;
  const float4* UeT4 = (const float4*)UeT;
  float4 acc[4];
  #pragma unroll
  for (int ii = 0; ii < 4; ++ii) acc[ii] = make_float4(0.f, 0.f, 0.f, 0.f);
  for (int t = 0; t < 128; ++t) {
    float4 w = UeT4[t * 32 + sl];
    #pragma unroll
    for (int ii = 0; ii < 4; ++ii) {
      float a = xs[t][ig + 8 * ii];
      FMA4(acc[ii], a, w);
    }
  }
  uint2* U2 = (uint2*)(AR + (size_t)b * 32768 + 16384);
  #pragma unroll
  for (int ii = 0; ii < 4; ++ii) {
    int i_loc = i0 + ig + 8 * ii;
    uint2 pk;
    pk.x = pk2(acc[ii].x, acc[ii].y);
    pk.y = pk2(acc[ii].z, acc[ii].w);
    U2[i_loc * 32 + sl] = pk;
  }
}

// ---------------------------------------------------------------------------
// Fused encoder -> udx -> decoder + head. 512 blocks * 512 threads, 2 rows.
__global__ __launch_bounds__(512, 4) void fused_k(
    const uint* __restrict__ WeH,  const uint* __restrict__ WencH,
    const float* __restrict__ benc, const float* __restrict__ Ve,
    const float* __restrict__ UdT,
    const uint* __restrict__ WdH,  const uint* __restrict__ WhhdH,
    const float* __restrict__ W1T, const float* __restrict__ bdec,
    const float* __restrict__ Vd,  const float* __restrict__ WihD,
    const float* __restrict__ Wt,  const float* __restrict__ btp,
    const float* __restrict__ b1,  const float* __restrict__ W2,
    const float* __restrict__ b2p, const float* __restrict__ yk,
    uint* __restrict__ AR, float* __restrict__ out)
{
  __shared__ __align__(16) float smemF[12288];   // 48 KB, phase-unioned
  float*  part  = smemF;                          // [4096] all phases
  float4* part4 = (float4*)smemF;
  // encoder overlay
  uint*  stE   = (uint*)(smemF + 4096);           // [512] row*256 + [h|c]pair
  uint*  xtH   = (uint*)(smemF + 4608);           // [128] row*64 + ipair
  float* ohs2  = smemF + 4736;                    // [256] row*128 + s
  float* bencS = smemF + 4992;                    // [1024]
  float* VeS   = smemF + 6016;                    // [128]
  float* redE  = smemF + 6144;                    // [8]
  // udx overlay
  float* xs    = smemF + 4096;                    // [8192] = [32][256]
  // decoder overlay
  uint*  stD   = (uint*)(smemF + 4096);           // [512]
  float* ods2  = smemF + 4608;                    // [512] row*256 + k
  float* cT    = smemF + 5120;                    // [512] row*256 + m
  float* betaS = smemF + 5632;                    // [256] row*128 + t
  float* wihdS = smemF + 5888;                    // [1024]
  float* bdecS = smemF + 6912;                    // [1024]
  float* VdS   = smemF + 7936;                    // [256]
  float* yts   = smemF + 8192;                    // [2]
  float* redD  = smemF + 8194;                    // [8]

  const int tid = threadIdx.x;
  const int b0 = blockIdx.x * 2;
  uint* ar0 = AR + (size_t)b0 * 32768;            // row b0 arena
  uint* ar1 = ar0 + 32768;                        // row b0+1 arena

  // ======================= ENCODER =======================
  stE[tid] = 0u;
  for (int i = tid; i < 1024; i += 512) bencS[i] = benc[i];
  if (tid < 128) VeS[tid] = Ve[tid];
  __syncthreads();

  float SVe = 0.f;
  for (int s = 0; s < 128; ++s) SVe += Ve[s];

  const uint4* WeH4   = (const uint4*)WeH;
  const uint4* WencH4 = (const uint4*)WencH;

  {
    const int rB = tid >> 8, iB = (tid >> 1) & 127, sh = tid & 1;
    const uint4* ux4 = (const uint4*)((rB ? ar1 : ar0) + 16384) + iB * 16 + sh * 8;
    float c_reg = 0.f;

    for (int step = 0; step < 128; ++step) {
      // A: ohs = hs @ We^T (K=512): 32 j4 x 16 ks, 16 kp each
      {
        const int j4 = tid & 31, ks = tid >> 5;
        float a0=0,a1=0,a2=0,a3=0,b0_=0,b1_=0,b2_=0,b3_=0;
        const int kb = ks * 16;
        __builtin_amdgcn_s_setprio(1);
        #pragma unroll 4
        for (int kp = kb; kp < kb + 16; ++kp) {
          uint4 w = WeH4[kp * 32 + j4];
          uint s0 = stE[kp], s1 = stE[256 + kp];
          float b0=b0_, b1=b1_, b2=b2_, b3=b3_;
          DOT8(w, s0, s1);
          b0_=b0; b1_=b1; b2_=b2; b3_=b3;
        }
        __builtin_amdgcn_s_setprio(0);
        part4[(ks * 2 + 0) * 32 + j4] = make_float4(a0, a1, a2, a3);
        part4[(ks * 2 + 1) * 32 + j4] = make_float4(b0_, b1_, b2_, b3_);
      }
      __syncthreads();
      if (tid < 256) {
        const int r = tid >> 7, j = tid & 127;
        float acc = 0.f;
        #pragma unroll
        for (int ks = 0; ks < 16; ++ks) acc += part[(ks * 2 + r) * 128 + j];
        ohs2[r * 128 + j] = acc * C2E;
      }
      __syncthreads();
      // B: e[i] = SVe - 2*sum_s Ve[s]*rcp(1+exp2(C2E*u + ohs2[s]))
      float e_val;
      {
        float a0 = 0.f, a1 = 0.f, a2 = 0.f, a3 = 0.f;
        const float* oh = ohs2 + rB * 128;
        #pragma unroll 4
        for (int so = 0; so < 8; ++so) {
          uint4 u = ux4[so];
          const int s = sh * 64 + so * 8;
          a0 += ATT_TERM(VeS[s+0], h2lo(u.x), oh[s+0]);
          a1 += ATT_TERM(VeS[s+1], h2hi(u.x), oh[s+1]);
          a2 += ATT_TERM(VeS[s+2], h2lo(u.y), oh[s+2]);
          a3 += ATT_TERM(VeS[s+3], h2hi(u.y), oh[s+3]);
          a0 += ATT_TERM(VeS[s+4], h2lo(u.z), oh[s+4]);
          a1 += ATT_TERM(VeS[s+5], h2hi(u.z), oh[s+5]);
          a2 += ATT_TERM(VeS[s+6], h2lo(u.w), oh[s+6]);
          a3 += ATT_TERM(VeS[s+7], h2hi(u.w), oh[s+7]);
        }
        float r4 = (a0 + a1) + (a2 + a3);
        r4 += __shfl_xor(r4, 1);
        e_val = fmaf(-2.f, r4, SVe);
      }
      // softmax (no max); quirk xt = alpha*e
      {
        float p  = __builtin_amdgcn_exp2f(L2E * e_val);
        float ps = (sh == 0) ? p : 0.f;
        #pragma unroll
        for (int o = 1; o < 64; o <<= 1) ps += __shfl_xor(ps, o);
        if ((tid & 63) == 0) redE[tid >> 6] = ps;
        __syncthreads();
        const int base = (tid >> 6) & 4;
        float sm = (redE[base+0] + redE[base+1]) + (redE[base+2] + redE[base+3]);
        float xt = p * __builtin_amdgcn_rcpf(sm) * e_val;
        float xn = __shfl_down(xt, 2);
        if ((tid & 3) == 0) xtH[rB * 64 + (iB >> 1)] = pk2(xt, xn);
      }
      __syncthreads();
      // D: gates = [xt;h] @ Wenc (K=384): 256 j4 x 2 ks, 96 kp each
      {
        const int j4 = tid & 255, ks = tid >> 8;
        float a0=0,a1=0,a2=0,a3=0,b0_=0,b1_=0,b2_=0,b3_=0;
        __builtin_amdgcn_s_setprio(1);
        if (ks == 0) {
          #pragma unroll 2
          for (int kp = 0; kp < 64; ++kp) {
            uint4 w = WencH4[kp * 256 + j4];
            uint s0 = xtH[kp], s1 = xtH[64 + kp];
            float b0=b0_, b1=b1_, b2=b2_, b3=b3_;
            DOT8(w, s0, s1);
            b0_=b0; b1_=b1; b2_=b2; b3_=b3;
          }
          #pragma unroll 2
          for (int kp = 64; kp < 96; ++kp) {
            uint4 w = WencH4[kp * 256 + j4];
            uint s0 = stE[kp - 64], s1 = stE[256 + kp - 64];
            float b0=b0_, b1=b1_, b2=b2_, b3=b3_;
            DOT8(w, s0, s1);
            b0_=b0; b1_=b1; b2_=b2; b3_=b3;
          }
        } else {
          #pragma unroll 2
          for (int kp = 96; kp < 192; ++kp) {
            uint4 w = WencH4[kp * 256 + j4];
            uint s0 = stE[kp - 64], s1 = stE[256 + kp - 64];
            float b0=b0_, b1=b1_, b2=b2_, b3=b3_;
            DOT8(w, s0, s1);
            b0_=b0; b1_=b1; b2_=b2; b3_=b3;
          }
        }
        __builtin_amdgcn_s_setprio(0);
        part4[(ks * 2 + 0) * 256 + j4] = make_float4(a0, a1, a2, a3);
        part4[(ks * 2 + 1) * 256 + j4] = make_float4(b0_, b1_, b2_, b3_);
      }
      __syncthreads();
      // update
      {
        const int r = tid >> 8, j = tid & 255;
        float z0 = bencS[j]       + part[r * 1024 + j]       + part[(2 + r) * 1024 + j];
        float z1 = bencS[256 + j] + part[r * 1024 + 256 + j] + part[(2 + r) * 1024 + 256 + j];
        float z2 = bencS[512 + j] + part[r * 1024 + 512 + j] + part[(2 + r) * 1024 + 512 + j];
        float z3 = bencS[768 + j] + part[r * 1024 + 768 + j] + part[(2 + r) * 1024 + 768 + j];
        float gi = fsig(z0), gf = fsig(z1), gg = fth(z2), go = fsig(z3);
        float c2 = fmaf(gf, c_reg, gi * gg);
        c_reg = c2;
        float h2 = go * fth(c2);
        float hn = __shfl_down(h2, 1);
        float cn = __shfl_down(c2, 1);
        if (!(j & 1)) {
          uint hp = pk2(h2, hn), cp = pk2(c2, cn);
          stE[r * 256 + (j >> 1)] = hp;
          stE[r * 256 + 128 + (j >> 1)] = cp;
          (r ? ar1 : ar0)[step * 128 + (j >> 1)] = hp;
        }
      }
      __syncthreads();
    }
  }

  // ======================= UDX =======================
  // Udx[t][k] = sum_m x1[t][m]*Ud[k][m] for own 2 rows; overwrites Ux region.
  {
    const float4* UdT4 = (const float4*)UdT;
    for (int sub = 0; sub < 8; ++sub) {
      const int r = sub >> 2, t0 = (sub & 3) * 32;
      const uint4* x14s = (const uint4*)(r ? ar1 : ar0);
      #pragma unroll
      for (int it = 0; it < 2; ++it) {
        int f = tid + it * 512;            // 1024 uint4 total
        int tl = f >> 5, mq = f & 31;
        uint4 u = x14s[(size_t)(t0 + tl) * 32 + mq];
        float* d = &xs[tl * 256 + mq * 8];
        d[0]=h2lo(u.x); d[1]=h2hi(u.x); d[2]=h2lo(u.y); d[3]=h2hi(u.y);
        d[4]=h2lo(u.z); d[5]=h2hi(u.z); d[6]=h2lo(u.w); d[7]=h2hi(u.w);
      }
      __syncthreads();
      const int kl = tid & 63, tg = tid >> 6;
      float4 acc[4];
      #pragma unroll
      for (int tt = 0; tt < 4; ++tt) acc[tt] = make_float4(0.f, 0.f, 0.f, 0.f);
      for (int m = 0; m < 256; ++m) {
        float4 w = UdT4[m * 64 + kl];
        #pragma unroll
        for (int tt = 0; tt < 4; ++tt) {
          float a = xs[(tg + 8 * tt) * 256 + m];
          FMA4(acc[tt], a, w);
        }
      }
      uint2* U2 = (uint2*)((r ? ar1 : ar0) + 16384);
      #pragma unroll
      for (int tt = 0; tt < 4; ++tt) {
        uint2 pk;
        pk.x = pk2(acc[tt].x, acc[tt].y);
        pk.y = pk2(acc[tt].z, acc[tt].w);
        U2[(size_t)(t0 + tg + 8 * tt) * 64 + kl] = pk;
      }
      __syncthreads();
    }
  }

  // ======================= DECODER =======================
  stD[tid] = 0u;
  for (int i = tid; i < 1024; i += 512) { wihdS[i] = WihD[i]; bdecS[i] = bdec[i]; }
  if (tid < 256) VdS[tid] = Vd[tid];
  __syncthreads();

  float SVd = 0.f;
  for (int k = 0; k < 256; ++k) SVd += Vd[k];

  const float bt0 = btp[0], Wt0 = Wt[0];
  const uint4*  WdH4   = (const uint4*)WdH;
  const uint4*  WhhdH4 = (const uint4*)WhhdH;
  const float4* W1T4   = (const float4*)W1T;

  const int rB = tid >> 8, tB = (tid >> 1) & 127, kh = tid & 1;
  const uint4* ud4 = (const uint4*)((rB ? ar1 : ar0) + 16384) + tB * 32 + kh * 16;
  const int m8 = tid & 31, rb2 = (tid >> 5) & 1, ts = tid >> 6;
  const uint4* x14 = (const uint4*)(rb2 ? ar1 : ar0) + m8;

  float c_reg = 0.f;

  for (int step = 0; step < 128; ++step) {
    float ykv = 0.f;
    if ((tid & 255) == 0) ykv = yk[(size_t)(b0 + (tid >> 8)) * 128 + step];
    // A: ods = ds @ Wd^T (K=512): 64 j4 x 8 ks, 32 kp each
    {
      const int j4 = tid & 63, ks = tid >> 6;
      float a0=0,a1=0,a2=0,a3=0,b0_=0,b1_=0,b2_=0,b3_=0;
      const int kb = ks * 32;
      __builtin_amdgcn_s_setprio(1);
      #pragma unroll 4
      for (int kp = kb; kp < kb + 32; ++kp) {
        uint4 w = WdH4[kp * 64 + j4];
        uint s0 = stD[kp], s1 = stD[256 + kp];
        float b0=b0_, b1=b1_, b2=b2_, b3=b3_;
        DOT8(w, s0, s1);
        b0_=b0; b1_=b1; b2_=b2; b3_=b3;
      }
      __builtin_amdgcn_s_setprio(0);
      part4[(ks * 2 + 0) * 64 + j4] = make_float4(a0, a1, a2, a3);
      part4[(ks * 2 + 1) * 64 + j4] = make_float4(b0_, b1_, b2_, b3_);
    }
    __syncthreads();
    {
      const int r = tid >> 8, kk = tid & 255;
      float acc = 0.f;
      #pragma unroll
      for (int ks = 0; ks < 8; ++ks) acc += part[(ks * 2 + r) * 256 + kk];
      ods2[r * 256 + kk] = acc * C2E;
    }
    __syncthreads();
    // B: l[t] = SVd - 2*sum_k Vd[k]*rcp(1+exp2(C2E*u + ods2[k]))
    float l_val;
    {
      float a0 = 0.f, a1 = 0.f, a2 = 0.f, a3 = 0.f;
      const float* od = ods2 + rB * 256;
      #pragma unroll 4
      for (int ko = 0; ko < 16; ++ko) {
        uint4 u = ud4[ko];
        const int k = kh * 128 + ko * 8;
        a0 += ATT_TERM(VdS[k+0], h2lo(u.x), od[k+0]);
        a1 += ATT_TERM(VdS[k+1], h2hi(u.x), od[k+1]);
        a2 += ATT_TERM(VdS[k+2], h2lo(u.y), od[k+2]);
        a3 += ATT_TERM(VdS[k+3], h2hi(u.y), od[k+3]);
        a0 += ATT_TERM(VdS[k+4], h2lo(u.z), od[k+4]);
        a1 += ATT_TERM(VdS[k+5], h2hi(u.z), od[k+5]);
        a2 += ATT_TERM(VdS[k+6], h2lo(u.w), od[k+6]);
        a3 += ATT_TERM(VdS[k+7], h2hi(u.w), od[k+7]);
      }
      float r4 = (a0 + a1) + (a2 + a3);
      r4 += __shfl_xor(r4, 1);
      l_val = fmaf(-2.f, r4, SVd);
    }
    // softmax over t (no max)
    {
      float p  = __builtin_amdgcn_exp2f(L2E * l_val);
      float ps = (kh == 0) ? p : 0.f;
      #pragma unroll
      for (int o = 1; o < 64; o <<= 1) ps += __shfl_xor(ps, o);
      if ((tid & 63) == 0) redD[tid >> 6] = ps;
      __syncthreads();
      const int base = (tid >> 6) & 4;
      float sm = (redD[base+0] + redD[base+1]) + (redD[base+2] + redD[base+3]);
      if (kh == 0) betaS[rB * 128 + tB] = p * __builtin_amdgcn_rcpf(sm);
    }
    __syncthreads();
    // C: c[m] = sum_t beta[t]*x1[t][m] (uint4 loads, 8 consecutive m/lane)
    {
      float c0=0,c1=0,c2=0,c3=0,c4=0,c5=0,c6=0,c7=0;
      const float* bS = betaS + rb2 * 128;
      #pragma unroll 4
      for (int tt = 0; tt < 16; ++tt) {
        const int t = ts * 16 + tt;
        float bv = bS[t];
        uint4 u = x14[(size_t)t * 32];
        c0 = fmaf(bv, h2lo(u.x), c0); c1 = fmaf(bv, h2hi(u.x), c1);
        c2 = fmaf(bv, h2lo(u.y), c2); c3 = fmaf(bv, h2hi(u.y), c3);
        c4 = fmaf(bv, h2lo(u.z), c4); c5 = fmaf(bv, h2hi(u.z), c5);
        c6 = fmaf(bv, h2lo(u.w), c6); c7 = fmaf(bv, h2hi(u.w), c7);
      }
      part4[(ts * 2 + rb2) * 64 + m8 * 2]     = make_float4(c0, c1, c2, c3);
      part4[(ts * 2 + rb2) * 64 + m8 * 2 + 1] = make_float4(c4, c5, c6, c7);
    }
    __syncthreads();
    // C-reduce + fused y_tilde row-dot
    {
      const int r = tid >> 8, m = tid & 255;
      float v = 0.f;
      #pragma unroll
      for (int t8 = 0; t8 < 8; ++t8) v += part[(t8 * 2 + r) * 256 + m];
      cT[r * 256 + m] = v;
      float pv = v * Wt[1 + m];
      #pragma unroll
      for (int o = 1; o < 64; o <<= 1) pv += __shfl_xor(pv, o);
      if ((tid & 63) == 0) redD[tid >> 6] = pv;
      __syncthreads();
      if ((tid & 255) == 0) {
        const int base = r * 4;
        float s = (redD[base] + redD[base+1]) + (redD[base+2] + redD[base+3]);
        yts[r] = s + ykv * Wt0 + bt0;
      }
    }
    // E: gates = d @ Whh_d^T (K=256): 256 j4 x 2 ks, 64 kp each
    {
      const int j4 = tid & 255, ks = tid >> 8;
      float a0=0,a1=0,a2=0,a3=0,b0_=0,b1_=0,b2_=0,b3_=0;
      const int kb = ks * 64;
      __builtin_amdgcn_s_setprio(1);
      #pragma unroll 2
      for (int kp = kb; kp < kb + 64; ++kp) {
        uint4 w = WhhdH4[kp * 256 + j4];
        uint s0 = stD[kp], s1 = stD[256 + kp];
        float b0=b0_, b1=b1_, b2=b2_, b3=b3_;
        DOT8(w, s0, s1);
        b0_=b0; b1_=b1; b2_=b2; b3_=b3;
      }
      __builtin_amdgcn_s_setprio(0);
      part4[(ks * 2 + 0) * 256 + j4] = make_float4(a0, a1, a2, a3);
      part4[(ks * 2 + 1) * 256 + j4] = make_float4(b0_, b1_, b2_, b3_);
    }
    __syncthreads();
    // update
    {
      const int r = tid >> 8, j = tid & 255;
      float yt = yts[r];
      float z0 = fmaf(yt, wihdS[j],       bdecS[j])       + part[r * 1024 + j]       + part[(2 + r) * 1024 + j];
      float z1 = fmaf(yt, wihdS[256 + j], bdecS[256 + j]) + part[r * 1024 + 256 + j] + part[(2 + r) * 1024 + 256 + j];
      float z2 = fmaf(yt, wihdS[512 + j], bdecS[512 + j]) + part[r * 1024 + 512 + j] + part[(2 + r) * 1024 + 512 + j];
      float z3 = fmaf(yt, wihdS[768 + j], bdecS[768 + j]) + part[r * 1024 + 768 + j] + part[(2 + r) * 1024 + 768 + j];
      float gi = fsig(z0), gf = fsig(z1), gg = fth(z2), go = fsig(z3);
      float c2 = fmaf(gf, c_reg, gi * gg);
      c_reg = c2;
      float d2 = go * fth(c2);
      float dn = __shfl_down(d2, 1);
      float cn = __shfl_down(c2, 1);
      if (!(j & 1)) {
        stD[r * 256 + (j >> 1)] = pk2(d2, dn);
        stD[r * 256 + 128 + (j >> 1)] = pk2(c2, cn);
      }
    }
    __syncthreads();
  }
  // --- final head: out1 = [d;c] @ W1^T + b1 ; out = out1 @ W2^T + b2
  {
    const int l = tid & 63, ks = tid >> 6;   // 8 ks x 64 k
    float a0=0,a1=0,a2=0,a3=0,b0_=0,b1_=0,b2_=0,b3_=0;
    const int kb = ks * 64;
    if (ks < 4) {
      for (int k = kb; k < kb + 64; ++k) {
        float4 w = W1T4[k * 64 + l];
        uint u0 = stD[k >> 1], u1 = stD[256 + (k >> 1)];
        float d0 = (k & 1) ? h2hi(u0) : h2lo(u0);
        float d1 = (k & 1) ? h2hi(u1) : h2lo(u1);
        a0=fmaf(d0,w.x,a0); a1=fmaf(d0,w.y,a1); a2=fmaf(d0,w.z,a2); a3=fmaf(d0,w.w,a3);
        b0_=fmaf(d1,w.x,b0_); b1_=fmaf(d1,w.y,b1_); b2_=fmaf(d1,w.z,b2_); b3_=fmaf(d1,w.w,b3_);
      }
    } else {
      for (int k = kb; k < kb + 64; ++k) {
        float4 w = W1T4[k * 64 + l];
        float c0 = cT[k - 256], c1 = cT[256 + k - 256];
        a0=fmaf(c0,w.x,a0); a1=fmaf(c0,w.y,a1); a2=fmaf(c0,w.z,a2); a3=fmaf(c0,w.w,a3);
        b0_=fmaf(c1,w.x,b0_); b1_=fmaf(c1,w.y,b1_); b2_=fmaf(c1,w.z,b2_); b3_=fmaf(c1,w.w,b3_);
      }
    }
    part4[(ks * 2 + 0) * 64 + l] = make_float4(a0, a1, a2, a3);
    part4[(ks * 2 + 1) * 64 + l] = make_float4(b0_, b1_, b2_, b3_);
  }
  __syncthreads();
  {
    const int r = tid >> 8, q = tid & 255;
    float o1 = b1[q];
    #pragma unroll
    for (int ks = 0; ks < 8; ++ks) o1 += part[(ks * 2 + r) * 256 + q];
    float pv = o1 * W2[q];
    #pragma unroll
    for (int o = 1; o < 64; o <<= 1) pv += __shfl_xor(pv, o);
    if ((tid & 63) == 0) redD[tid >> 6] = pv;
    __syncthreads();
    if ((tid & 255) == 0) {
      const int base = r * 4;
      float s = (redD[base] + redD[base+1]) + (redD[base+2] + redD[base+3]);
      out[b0 + r] = s + b2p[0];
    }
  }
}

// ---------------------------------------------------------------------------
extern "C" void kernel_launch(void* const* d_in, const int* in_sizes, int n_in,
                              void* d_out, int out_size, void* d_ws, size_t ws_size,
                              hipStream_t stream)
{
  const float* x       = (const float*)d_in[0];
  const float* y_known = (const float*)d_in[1];
  const float* We      = (const float*)d_in[2];
  const float* Ue      = (const float*)d_in[3];
  const float* Ve      = (const float*)d_in[4];
  const float* Wih_e   = (const float*)d_in[5];
  const float* Whh_e   = (const float*)d_in[6];
  const float* bih_e   = (const float*)d_in[7];
  const float* bhh_e   = (const float*)d_in[8];
  const float* Wd      = (const float*)d_in[9];
  const float* Ud      = (const float*)d_in[10];
  const float* Vd      = (const float*)d_in[11];
  const float* Wih_d   = (const float*)d_in[12];
  const float* Whh_d   = (const float*)d_in[13];
  const float* bih_d   = (const float*)d_in[14];
  const float* bhh_d   = (const float*)d_in[15];
  const float* Wt      = (const float*)d_in[16];
  const float* bt      = (const float*)d_in[17];
  const float* W1      = (const float*)d_in[18];
  const float* b1      = (const float*)d_in[19];
  const float* W2      = (const float*)d_in[20];
  const float* b2      = (const float*)d_in[21];

  float* ws  = (float*)d_ws;
  float* out = (float*)d_out;
  if (ws_size < (size_t)WS_FLOATS * 4u) return;

  uint* wsu = (uint*)ws;
  uint* AR  = (uint*)(ws + O_AR);

  prep_k<<<(W_FLOATS + 255) / 256, 256, 0, stream>>>(
      We, Wih_e, Whh_e, Wd, Whh_d, W1, Ud, Ue,
      bih_e, bhh_e, bih_d, bhh_d, ws);

  ux_k<<<4096, 256, 0, stream>>>(x, ws + O_UET, AR);
  fused_k<<<512, 512, 0, stream>>>(wsu + O_WEH, wsu + O_WENCH,
                                   ws + O_BENC, Ve, ws + O_UDT,
                                   wsu + O_WDH, wsu + O_WHHDH,
                                   ws + O_W1T, ws + O_BDEC, Vd, Wih_d,
                                   Wt, bt, b1, W2, b2, y_known,
                                   AR, out);
}